// Round 5
// baseline (961.139 us; speedup 1.0000x reference)
//
#include <hip/hip_runtime.h>

#define N_NODES 50000
#define N_EDGES 1600000
#define DIM_IN  512
#define DIM_HID 64
#define DIM_OUT 7

using u16 = unsigned short;

__device__ __forceinline__ float bf2f(u16 u) {
    union { float f; unsigned int i; } v;
    v.i = ((unsigned int)u) << 16;
    return v.f;
}

__device__ __forceinline__ u16 f2bf(float f) {
    union { float f; unsigned int i; } v;
    v.f = f;
    unsigned int r = 0x7FFFu + ((v.i >> 16) & 1u);
    return (u16)((v.i + r) >> 16);
}

// ---- on-device input-encoding detection (proven in rounds 2-4) ----
// flags[0]: 1 if float tensors are f32, 0 if bf16
// flags[1]: 1 if edge_index is int64, 0 if int32
__global__ void k_detect(const u16* __restrict__ xw, const int* __restrict__ ei32,
                         int* __restrict__ flags) {
    if (threadIdx.x == 0 && blockIdx.x == 0) {
        int sane = 0;
        for (int i = 0; i < 256; ++i) {
            u16 w = xw[2 * i];
            int e = (w >> 7) & 0xFF;
            if (e >= 100 && e <= 140) sane++;
        }
        flags[0] = (sane >= 200) ? 0 : 1;
        int nz = 0;
        for (int i = 0; i < 256; ++i)
            if (ei32[2 * i + 1] != 0) nz++;
        flags[1] = (nz == 0) ? 1 : 0;
    }
}

__device__ __forceinline__ int ld_edge(const int* ei, int i64f, size_t idx) {
    if (i64f) return (int)((const long long*)ei)[idx];
    return ei[idx];
}

__global__ void k_deg(const int* __restrict__ ei, const int* __restrict__ flags,
                      int* __restrict__ deg) {
    int i = blockIdx.x * blockDim.x + threadIdx.x;
    if (i < N_EDGES) {
        int d = ld_edge(ei, flags[1], (size_t)N_EDGES + i);
        if ((unsigned)d < (unsigned)N_NODES) atomicAdd(&deg[d], 1);
    }
}

__global__ void k_dinv(const int* __restrict__ deg, float* __restrict__ dinv) {
    int i = blockIdx.x * blockDim.x + threadIdx.x;
    if (i < N_NODES) dinv[i] = rsqrtf((float)(deg[i] + 1));
}

__global__ void k_scan(const int* __restrict__ deg, int* __restrict__ rowptr,
                       int* __restrict__ cursor) {
    __shared__ int part[1024];
    const int C = (N_NODES + 1023) / 1024;
    int t = threadIdx.x;
    int base = t * C;
    int s = 0;
    for (int i = 0; i < C; ++i) {
        int idx = base + i;
        if (idx < N_NODES) s += deg[idx];
    }
    part[t] = s;
    __syncthreads();
    for (int off = 1; off < 1024; off <<= 1) {
        int v = (t >= off) ? part[t - off] : 0;
        __syncthreads();
        part[t] += v;
        __syncthreads();
    }
    int run = part[t] - s;
    for (int i = 0; i < C; ++i) {
        int idx = base + i;
        if (idx < N_NODES) {
            rowptr[idx] = run;
            cursor[idx] = run;
            run += deg[idx];
        }
    }
    if (t == 1023) rowptr[N_NODES] = part[1023];
}

__global__ void k_fill(const int* __restrict__ ei, const int* __restrict__ flags,
                       int* __restrict__ cursor, int* __restrict__ col) {
    int i = blockIdx.x * blockDim.x + threadIdx.x;
    if (i < N_EDGES) {
        int i64f = flags[1];
        int s = ld_edge(ei, i64f, (size_t)i);
        int d = ld_edge(ei, i64f, (size_t)N_EDGES + i);
        if ((unsigned)d < (unsigned)N_NODES && (unsigned)s < (unsigned)N_NODES) {
            int p = atomicAdd(&cursor[d], 1);
            if ((unsigned)p < (unsigned)N_EDGES) col[p] = s;
        }
    }
}

// ---- GEMM1 (VALU): hs[n][h] = dot(x[n], W1[:,h]) * dinv[n], stored bf16 ----
// block = 256 = 4 nodes x 64 hid; W1[k*64+h] coalesced; x[n][k] wave-uniform.
__launch_bounds__(256)
__global__ void k_gemm1v(const void* __restrict__ xraw, const void* __restrict__ W1,
                         const int* __restrict__ flags, const float* __restrict__ dinv,
                         u16* __restrict__ hs) {
    int f32f = flags[0];
    int wave = threadIdx.x >> 6;
    int lane = threadIdx.x & 63;
    int node = blockIdx.x * 4 + wave;
    if (node >= N_NODES) return;

    float acc = 0.f;
    if (f32f) {
        const float* xf = (const float*)xraw + (size_t)node * DIM_IN;
        const float* Wf = (const float*)W1;
#pragma unroll 4
        for (int k = 0; k < DIM_IN; k += 4) {
            float4 xv = *reinterpret_cast<const float4*>(xf + k);
            acc += xv.x * Wf[(k + 0) * DIM_HID + lane];
            acc += xv.y * Wf[(k + 1) * DIM_HID + lane];
            acc += xv.z * Wf[(k + 2) * DIM_HID + lane];
            acc += xv.w * Wf[(k + 3) * DIM_HID + lane];
        }
    } else {
        const u16* xb = (const u16*)xraw + (size_t)node * DIM_IN;
        const u16* Wb = (const u16*)W1;
#pragma unroll 4
        for (int k = 0; k < DIM_IN; k += 4) {
            ushort4 xv = *reinterpret_cast<const ushort4*>(xb + k);
            acc += bf2f(xv.x) * bf2f(Wb[(k + 0) * DIM_HID + lane]);
            acc += bf2f(xv.y) * bf2f(Wb[(k + 1) * DIM_HID + lane]);
            acc += bf2f(xv.z) * bf2f(Wb[(k + 2) * DIM_HID + lane]);
            acc += bf2f(xv.w) * bf2f(Wb[(k + 3) * DIM_HID + lane]);
        }
    }
    hs[(size_t)node * DIM_HID + lane] = f2bf(acc * dinv[node]);
}

// ---- layer-1 pull aggregation + fused GEMM2 (64->7) ----
__launch_bounds__(256)
__global__ void k_agg1(const u16* __restrict__ hs, const int* __restrict__ rowptr,
                       const int* __restrict__ col, const float* __restrict__ dinv,
                       const void* __restrict__ b1, const void* __restrict__ W2,
                       const int* __restrict__ flags, float* __restrict__ zs) {
    int f32f = flags[0];
    int wave = threadIdx.x >> 6;
    int lane = threadIdx.x & 63;
    int d = blockIdx.x * 4 + wave;
    if (d >= N_NODES) return;
    int start = rowptr[d], end = rowptr[d + 1];
    if (start < 0) start = 0;
    if (end > N_EDGES) end = N_EDGES;
    if (end < start) end = start;

    float acc = 0.f;
    int e = start;
    for (; e + 4 <= end; e += 4) {
        int s0 = col[e], s1 = col[e + 1], s2 = col[e + 2], s3 = col[e + 3];
        float v0 = bf2f(hs[(size_t)s0 * DIM_HID + lane]);
        float v1 = bf2f(hs[(size_t)s1 * DIM_HID + lane]);
        float v2 = bf2f(hs[(size_t)s2 * DIM_HID + lane]);
        float v3 = bf2f(hs[(size_t)s3 * DIM_HID + lane]);
        acc += v0 + v1 + v2 + v3;
    }
    for (; e < end; ++e) acc += bf2f(hs[(size_t)col[e] * DIM_HID + lane]);
    acc += bf2f(hs[(size_t)d * DIM_HID + lane]);  // self loop

    float b1v = f32f ? ((const float*)b1)[lane] : bf2f(((const u16*)b1)[lane]);
    float dv = dinv[d];
    float h2 = fmaxf(acc * dv + b1v, 0.f);  // relu(agg + b1)

    float p[7];
#pragma unroll
    for (int f = 0; f < 7; ++f) {
        float w = f32f ? ((const float*)W2)[lane * DIM_OUT + f]
                       : bf2f(((const u16*)W2)[lane * DIM_OUT + f]);
        p[f] = h2 * w;
    }
#pragma unroll
    for (int off = 32; off >= 1; off >>= 1) {
#pragma unroll
        for (int f = 0; f < 7; ++f) p[f] += __shfl_xor(p[f], off);
    }
    if (lane == 0) {
#pragma unroll
        for (int f = 0; f < 7; ++f) zs[(size_t)d * 8 + f] = p[f] * dv;
        zs[(size_t)d * 8 + 7] = 0.f;
    }
}

// ---- layer-2 pull aggregation: out (f32!) = dinv*(sum zs[src] + zs[d]) + b2 ----
__launch_bounds__(256)
__global__ void k_agg2(const float* __restrict__ zs, const int* __restrict__ rowptr,
                       const int* __restrict__ col, const float* __restrict__ dinv,
                       const void* __restrict__ b2, const int* __restrict__ flags,
                       float* __restrict__ out) {
    int f32f = flags[0];
    int wave = threadIdx.x >> 6;
    int lane = threadIdx.x & 63;
    int d = blockIdx.x * 4 + wave;
    if (d >= N_NODES) return;
    int f = lane & 7;
    int g = lane >> 3;
    int start = rowptr[d], end = rowptr[d + 1];
    if (start < 0) start = 0;
    if (end > N_EDGES) end = N_EDGES;
    if (end < start) end = start;

    float acc = 0.f;
    for (int e = start + g; e < end; e += 8)
        acc += zs[(size_t)col[e] * 8 + f];

    acc += __shfl_xor(acc, 8);
    acc += __shfl_xor(acc, 16);
    acc += __shfl_xor(acc, 32);

    if (lane < 7) {
        float b2v = f32f ? ((const float*)b2)[lane] : bf2f(((const u16*)b2)[lane]);
        float tot = (acc + zs[(size_t)d * 8 + lane]) * dinv[d] + b2v;
        out[(size_t)d * DIM_OUT + lane] = tot;  // FULL-WIDTH f32 OUTPUT
    }
}

extern "C" void kernel_launch(void* const* d_in, const int* in_sizes, int n_in,
                              void* d_out, int out_size, void* d_ws, size_t ws_size,
                              hipStream_t stream) {
    const void* x  = d_in[0];
    const int*  ei = (const int*)d_in[1];
    const void* W1 = d_in[2];
    const void* b1 = d_in[3];
    const void* W2 = d_in[4];
    const void* b2 = d_in[5];

    char* ws = (char*)d_ws;
    size_t off = 0;
    auto alloc = [&](size_t bytes) -> void* {
        void* p = ws + off;
        off = (off + bytes + 255) & ~(size_t)255;
        return p;
    };
    int*   flags  = (int*)alloc(32);
    int*   deg    = (int*)alloc((size_t)N_NODES * 4);
    int*   rowptr = (int*)alloc((size_t)(N_NODES + 1) * 4);
    int*   cursor = (int*)alloc((size_t)N_NODES * 4);
    float* dinv   = (float*)alloc((size_t)N_NODES * 4);
    int*   colb   = (int*)alloc((size_t)N_EDGES * 4);
    u16*   hs     = (u16*)alloc((size_t)N_NODES * DIM_HID * 2);
    float* zs     = (float*)alloc((size_t)N_NODES * 8 * 4);
    float* out    = (float*)d_out;

    hipMemsetAsync(deg, 0, (size_t)N_NODES * 4, stream);
    k_detect<<<1, 64, 0, stream>>>((const u16*)x, ei, flags);
    k_deg <<<(N_EDGES + 255) / 256, 256, 0, stream>>>(ei, flags, deg);
    k_dinv<<<(N_NODES + 255) / 256, 256, 0, stream>>>(deg, dinv);
    k_scan<<<1, 1024, 0, stream>>>(deg, rowptr, cursor);
    k_fill<<<(N_EDGES + 255) / 256, 256, 0, stream>>>(ei, flags, cursor, colb);
    k_gemm1v<<<(N_NODES + 3) / 4, 256, 0, stream>>>(x, W1, flags, dinv, hs);
    k_agg1<<<(N_NODES + 3) / 4, 256, 0, stream>>>(hs, rowptr, colb, dinv, b1, W2, flags, zs);
    k_agg2<<<(N_NODES + 3) / 4, 256, 0, stream>>>(zs, rowptr, colb, dinv, b2, flags, out);
}

// Round 6
// 610.855 us; speedup vs baseline: 1.5734x; 1.5734x over previous
//
#include <hip/hip_runtime.h>

#define N_NODES 50000
#define N_EDGES 1600000
#define DIM_IN  512
#define DIM_HID 64
#define DIM_OUT 7

using u16 = unsigned short;
using bf16x8 = __attribute__((ext_vector_type(8))) __bf16;
using f32x4  = __attribute__((ext_vector_type(4))) float;

__device__ __forceinline__ float bf2f(u16 u) {
    union { float f; unsigned int i; } v;
    v.i = ((unsigned int)u) << 16;
    return v.f;
}

__device__ __forceinline__ u16 f2bf(float f) {
    union { float f; unsigned int i; } v;
    v.f = f;
    unsigned int r = 0x7FFFu + ((v.i >> 16) & 1u);
    return (u16)((v.i + r) >> 16);
}

// ---- on-device input-encoding detection (proven rounds 2-5) ----
// flags[0]: 1 if float tensors are f32, 0 if bf16
// flags[1]: 1 if edge_index is int64, 0 if int32
__global__ void k_detect(const u16* __restrict__ xw, const int* __restrict__ ei32,
                         int* __restrict__ flags) {
    if (threadIdx.x == 0 && blockIdx.x == 0) {
        int sane = 0;
        for (int i = 0; i < 256; ++i) {
            u16 w = xw[2 * i];
            int e = (w >> 7) & 0xFF;
            if (e >= 100 && e <= 140) sane++;
        }
        flags[0] = (sane >= 200) ? 0 : 1;
        int nz = 0;
        for (int i = 0; i < 256; ++i)
            if (ei32[2 * i + 1] != 0) nz++;
        flags[1] = (nz == 0) ? 1 : 0;
    }
}

__device__ __forceinline__ int ld_edge(const int* ei, int i64f, size_t idx) {
    if (i64f) return (int)((const long long*)ei)[idx];
    return ei[idx];
}

__global__ void k_deg(const int* __restrict__ ei, const int* __restrict__ flags,
                      int* __restrict__ deg) {
    int i = blockIdx.x * blockDim.x + threadIdx.x;
    if (i < N_EDGES) {
        int d = ld_edge(ei, flags[1], (size_t)N_EDGES + i);
        if ((unsigned)d < (unsigned)N_NODES) atomicAdd(&deg[d], 1);
    }
}

__global__ void k_dinv(const int* __restrict__ deg, float* __restrict__ dinv) {
    int i = blockIdx.x * blockDim.x + threadIdx.x;
    if (i < N_NODES) dinv[i] = rsqrtf((float)(deg[i] + 1));
}

__global__ void k_scan(const int* __restrict__ deg, int* __restrict__ rowptr,
                       int* __restrict__ cursor) {
    __shared__ int part[1024];
    const int C = (N_NODES + 1023) / 1024;
    int t = threadIdx.x;
    int base = t * C;
    int s = 0;
    for (int i = 0; i < C; ++i) {
        int idx = base + i;
        if (idx < N_NODES) s += deg[idx];
    }
    part[t] = s;
    __syncthreads();
    for (int off = 1; off < 1024; off <<= 1) {
        int v = (t >= off) ? part[t - off] : 0;
        __syncthreads();
        part[t] += v;
        __syncthreads();
    }
    int run = part[t] - s;
    for (int i = 0; i < C; ++i) {
        int idx = base + i;
        if (idx < N_NODES) {
            rowptr[idx] = run;
            cursor[idx] = run;
            run += deg[idx];
        }
    }
    if (t == 1023) rowptr[N_NODES] = part[1023];
}

__global__ void k_fill(const int* __restrict__ ei, const int* __restrict__ flags,
                       int* __restrict__ cursor, int* __restrict__ col) {
    int i = blockIdx.x * blockDim.x + threadIdx.x;
    if (i < N_EDGES) {
        int i64f = flags[1];
        int s = ld_edge(ei, i64f, (size_t)i);
        int d = ld_edge(ei, i64f, (size_t)N_EDGES + i);
        if ((unsigned)d < (unsigned)N_NODES && (unsigned)s < (unsigned)N_NODES) {
            int p = atomicAdd(&cursor[d], 1);
            if ((unsigned)p < (unsigned)N_EDGES) col[p] = s;
        }
    }
}

// ---- W1T[n][k] = bf16(W1[k][n]) ----
__global__ void k_tw1(const void* __restrict__ W1, const int* __restrict__ flags,
                      u16* __restrict__ W1T) {
    int i = blockIdx.x * blockDim.x + threadIdx.x;
    if (i < DIM_IN * DIM_HID) {
        int n = i >> 9;       // /512
        int k = i & 511;
        if (flags[0]) W1T[i] = f2bf(((const float*)W1)[k * DIM_HID + n]);
        else          W1T[i] = ((const u16*)W1)[k * DIM_HID + n];
    }
}

// ---- GEMM1 (MFMA 16x16x32 bf16): hs = bf16((x @ W1) * dinv[row]) ----
// block = 256 = 4 waves; wave computes 16 rows x 64 cols; 64 rows/block.
__launch_bounds__(256)
__global__ void k_gemm1(const void* __restrict__ xraw, const u16* __restrict__ W1T,
                        const int* __restrict__ flags, const float* __restrict__ dinv,
                        u16* __restrict__ hs) {
    int f32f = flags[0];
    int wave = threadIdx.x >> 6;
    int lane = threadIdx.x & 63;
    int m16 = lane & 15;
    int quad = lane >> 4;
    int rbase = blockIdx.x * 64 + wave * 16;
    int ra = rbase + m16;
    if (ra > N_NODES - 1) ra = N_NODES - 1;  // clamp loads; stores guarded
    const u16*   xrow_b = (const u16*)xraw   + (size_t)ra * DIM_IN + quad * 8;
    const float* xrow_f = (const float*)xraw + (size_t)ra * DIM_IN + quad * 8;
    const u16* wrow = W1T + (size_t)m16 * DIM_IN + quad * 8;

    f32x4 acc0 = {0.f, 0.f, 0.f, 0.f};
    f32x4 acc1 = {0.f, 0.f, 0.f, 0.f};
    f32x4 acc2 = {0.f, 0.f, 0.f, 0.f};
    f32x4 acc3 = {0.f, 0.f, 0.f, 0.f};

    for (int ks = 0; ks < DIM_IN / 32; ++ks) {
        bf16x8 a;
        if (f32f) {
            const float4* q = reinterpret_cast<const float4*>(xrow_f + ks * 32);
            float4 p0 = q[0], p1 = q[1];
            union { bf16x8 v; u16 s[8]; } u;
            u.s[0] = f2bf(p0.x); u.s[1] = f2bf(p0.y); u.s[2] = f2bf(p0.z); u.s[3] = f2bf(p0.w);
            u.s[4] = f2bf(p1.x); u.s[5] = f2bf(p1.y); u.s[6] = f2bf(p1.z); u.s[7] = f2bf(p1.w);
            a = u.v;
        } else {
            a = *reinterpret_cast<const bf16x8*>(xrow_b + ks * 32);
        }
        bf16x8 b0 = *reinterpret_cast<const bf16x8*>(wrow + ks * 32);
        bf16x8 b1 = *reinterpret_cast<const bf16x8*>(wrow + ks * 32 + 16 * DIM_IN);
        bf16x8 b2 = *reinterpret_cast<const bf16x8*>(wrow + ks * 32 + 32 * DIM_IN);
        bf16x8 b3 = *reinterpret_cast<const bf16x8*>(wrow + ks * 32 + 48 * DIM_IN);
        acc0 = __builtin_amdgcn_mfma_f32_16x16x32_bf16(a, b0, acc0, 0, 0, 0);
        acc1 = __builtin_amdgcn_mfma_f32_16x16x32_bf16(a, b1, acc1, 0, 0, 0);
        acc2 = __builtin_amdgcn_mfma_f32_16x16x32_bf16(a, b2, acc2, 0, 0, 0);
        acc3 = __builtin_amdgcn_mfma_f32_16x16x32_bf16(a, b3, acc3, 0, 0, 0);
    }

    // C/D layout: col = lane&15, row = quad*4 + reg  [m89-verified]
#pragma unroll
    for (int i = 0; i < 4; ++i) {
        int r = rbase + quad * 4 + i;
        if (r < N_NODES) {
            float dv = dinv[r];
            u16* orow = hs + (size_t)r * DIM_HID;
            orow[ 0 + m16] = f2bf(acc0[i] * dv);
            orow[16 + m16] = f2bf(acc1[i] * dv);
            orow[32 + m16] = f2bf(acc2[i] * dv);
            orow[48 + m16] = f2bf(acc3[i] * dv);
        }
    }
}

// ---- layer-1 pull aggregation + fused GEMM2 (64->7) ----
__launch_bounds__(256)
__global__ void k_agg1(const u16* __restrict__ hs, const int* __restrict__ rowptr,
                       const int* __restrict__ col, const float* __restrict__ dinv,
                       const void* __restrict__ b1, const void* __restrict__ W2,
                       const int* __restrict__ flags, float* __restrict__ zs) {
    int f32f = flags[0];
    int wave = threadIdx.x >> 6;
    int lane = threadIdx.x & 63;
    int d = blockIdx.x * 4 + wave;
    if (d >= N_NODES) return;
    int start = rowptr[d], end = rowptr[d + 1];
    if (start < 0) start = 0;
    if (end > N_EDGES) end = N_EDGES;
    if (end < start) end = start;

    float acc = 0.f;
    int e = start;
    for (; e + 4 <= end; e += 4) {
        int s0 = col[e], s1 = col[e + 1], s2 = col[e + 2], s3 = col[e + 3];
        float v0 = bf2f(hs[(size_t)s0 * DIM_HID + lane]);
        float v1 = bf2f(hs[(size_t)s1 * DIM_HID + lane]);
        float v2 = bf2f(hs[(size_t)s2 * DIM_HID + lane]);
        float v3 = bf2f(hs[(size_t)s3 * DIM_HID + lane]);
        acc += v0 + v1 + v2 + v3;
    }
    for (; e < end; ++e) acc += bf2f(hs[(size_t)col[e] * DIM_HID + lane]);
    acc += bf2f(hs[(size_t)d * DIM_HID + lane]);  // self loop

    float b1v = f32f ? ((const float*)b1)[lane] : bf2f(((const u16*)b1)[lane]);
    float dv = dinv[d];
    float h2 = fmaxf(acc * dv + b1v, 0.f);  // relu(agg + b1)

    float p[7];
#pragma unroll
    for (int f = 0; f < 7; ++f) {
        float w = f32f ? ((const float*)W2)[lane * DIM_OUT + f]
                       : bf2f(((const u16*)W2)[lane * DIM_OUT + f]);
        p[f] = h2 * w;
    }
#pragma unroll
    for (int off = 32; off >= 1; off >>= 1) {
#pragma unroll
        for (int f = 0; f < 7; ++f) p[f] += __shfl_xor(p[f], off);
    }
    if (lane == 0) {
#pragma unroll
        for (int f = 0; f < 7; ++f) zs[(size_t)d * 8 + f] = p[f] * dv;
        zs[(size_t)d * 8 + 7] = 0.f;
    }
}

// ---- layer-2 pull aggregation: out (f32) = dinv*(sum zs[src] + zs[d]) + b2 ----
__launch_bounds__(256)
__global__ void k_agg2(const float* __restrict__ zs, const int* __restrict__ rowptr,
                       const int* __restrict__ col, const float* __restrict__ dinv,
                       const void* __restrict__ b2, const int* __restrict__ flags,
                       float* __restrict__ out) {
    int f32f = flags[0];
    int wave = threadIdx.x >> 6;
    int lane = threadIdx.x & 63;
    int d = blockIdx.x * 4 + wave;
    if (d >= N_NODES) return;
    int f = lane & 7;
    int g = lane >> 3;
    int start = rowptr[d], end = rowptr[d + 1];
    if (start < 0) start = 0;
    if (end > N_EDGES) end = N_EDGES;
    if (end < start) end = start;

    float acc = 0.f;
    for (int e = start + g; e < end; e += 8)
        acc += zs[(size_t)col[e] * 8 + f];

    acc += __shfl_xor(acc, 8);
    acc += __shfl_xor(acc, 16);
    acc += __shfl_xor(acc, 32);

    if (lane < 7) {
        float b2v = f32f ? ((const float*)b2)[lane] : bf2f(((const u16*)b2)[lane]);
        float tot = (acc + zs[(size_t)d * 8 + lane]) * dinv[d] + b2v;
        out[(size_t)d * DIM_OUT + lane] = tot;
    }
}

extern "C" void kernel_launch(void* const* d_in, const int* in_sizes, int n_in,
                              void* d_out, int out_size, void* d_ws, size_t ws_size,
                              hipStream_t stream) {
    const void* x  = d_in[0];
    const int*  ei = (const int*)d_in[1];
    const void* W1 = d_in[2];
    const void* b1 = d_in[3];
    const void* W2 = d_in[4];
    const void* b2 = d_in[5];

    char* ws = (char*)d_ws;
    size_t off = 0;
    auto alloc = [&](size_t bytes) -> void* {
        void* p = ws + off;
        off = (off + bytes + 255) & ~(size_t)255;
        return p;
    };
    int*   flags  = (int*)alloc(32);
    int*   deg    = (int*)alloc((size_t)N_NODES * 4);
    int*   rowptr = (int*)alloc((size_t)(N_NODES + 1) * 4);
    int*   cursor = (int*)alloc((size_t)N_NODES * 4);
    float* dinv   = (float*)alloc((size_t)N_NODES * 4);
    u16*   W1T    = (u16*)alloc((size_t)DIM_IN * DIM_HID * 2);
    int*   colb   = (int*)alloc((size_t)N_EDGES * 4);
    u16*   hs     = (u16*)alloc((size_t)N_NODES * DIM_HID * 2);
    float* zs     = (float*)alloc((size_t)N_NODES * 8 * 4);
    float* out    = (float*)d_out;

    hipMemsetAsync(deg, 0, (size_t)N_NODES * 4, stream);
    k_detect<<<1, 64, 0, stream>>>((const u16*)x, ei, flags);
    k_deg <<<(N_EDGES + 255) / 256, 256, 0, stream>>>(ei, flags, deg);
    k_dinv<<<(N_NODES + 255) / 256, 256, 0, stream>>>(deg, dinv);
    k_scan<<<1, 1024, 0, stream>>>(deg, rowptr, cursor);
    k_fill<<<(N_EDGES + 255) / 256, 256, 0, stream>>>(ei, flags, cursor, colb);
    k_tw1 <<<(DIM_IN * DIM_HID + 255) / 256, 256, 0, stream>>>(W1, flags, W1T);
    k_gemm1<<<(N_NODES + 63) / 64, 256, 0, stream>>>(x, W1T, flags, dinv, hs);
    k_agg1<<<(N_NODES + 3) / 4, 256, 0, stream>>>(hs, rowptr, colb, dinv, b1, W2, flags, zs);
    k_agg2<<<(N_NODES + 3) / 4, 256, 0, stream>>>(zs, rowptr, colb, dinv, b2, flags, out);
}

// Round 7
// 421.584 us; speedup vs baseline: 2.2798x; 1.4490x over previous
//
#include <hip/hip_runtime.h>

#define N_NODES 50000
#define N_EDGES 1600000
#define DIM_IN  512
#define DIM_HID 64
#define DIM_OUT 7
#define NBUCK   196   // ceil(N_NODES/256)

using u16 = unsigned short;
using bf16x8 = __attribute__((ext_vector_type(8))) __bf16;
using f32x4  = __attribute__((ext_vector_type(4))) float;

__device__ __forceinline__ float bf2f(u16 u) {
    union { float f; unsigned int i; } v;
    v.i = ((unsigned int)u) << 16;
    return v.f;
}

__device__ __forceinline__ u16 f2bf(float f) {
    union { float f; unsigned int i; } v;
    v.f = f;
    unsigned int r = 0x7FFFu + ((v.i >> 16) & 1u);
    return (u16)((v.i + r) >> 16);
}

// ---- on-device input-encoding detection (proven rounds 2-6) ----
__global__ void k_detect(const u16* __restrict__ xw, const int* __restrict__ ei32,
                         int* __restrict__ flags) {
    if (threadIdx.x == 0 && blockIdx.x == 0) {
        int sane = 0;
        for (int i = 0; i < 256; ++i) {
            u16 w = xw[2 * i];
            int e = (w >> 7) & 0xFF;
            if (e >= 100 && e <= 140) sane++;
        }
        flags[0] = (sane >= 200) ? 0 : 1;
        int nz = 0;
        for (int i = 0; i < 256; ++i)
            if (ei32[2 * i + 1] != 0) nz++;
        flags[1] = (nz == 0) ? 1 : 0;
    }
}

__device__ __forceinline__ int ld_edge(const int* ei, int i64f, size_t idx) {
    if (i64f) return (int)((const long long*)ei)[idx];
    return ei[idx];
}

// ---- degree histogram (predicate identical to k_part: BOTH endpoints valid) ----
__global__ void k_deg(const int* __restrict__ ei, const int* __restrict__ flags,
                      int* __restrict__ deg) {
    int i = blockIdx.x * blockDim.x + threadIdx.x;
    if (i < N_EDGES) {
        int i64f = flags[1];
        int s = ld_edge(ei, i64f, (size_t)i);
        int d = ld_edge(ei, i64f, (size_t)N_EDGES + i);
        if ((unsigned)d < (unsigned)N_NODES && (unsigned)s < (unsigned)N_NODES)
            atomicAdd(&deg[d], 1);
    }
}

__global__ void k_dinv(const int* __restrict__ deg, float* __restrict__ dinv) {
    int i = blockIdx.x * blockDim.x + threadIdx.x;
    if (i < N_NODES) dinv[i] = rsqrtf((float)(deg[i] + 1));
}

// ---- hierarchical scan, stage 1: per-bucket sums ----
__global__ void k_s1(const int* __restrict__ deg, int* __restrict__ bsum) {
    __shared__ int red[256];
    int b = blockIdx.x, t = threadIdx.x;
    int idx = b * 256 + t;
    red[t] = (idx < N_NODES) ? deg[idx] : 0;
    __syncthreads();
    for (int off = 128; off >= 1; off >>= 1) {
        if (t < off) red[t] += red[t + off];
        __syncthreads();
    }
    if (t == 0) bsum[b] = red[0];
}

// ---- stage 2: exclusive scan of bucket sums -> bbase (=bucket cursor) ----
__global__ void k_s2(const int* __restrict__ bsum, int* __restrict__ bbase,
                     int* __restrict__ bcur, int* __restrict__ rowptr) {
    __shared__ int sc[256];
    int t = threadIdx.x;
    int v = (t < NBUCK) ? bsum[t] : 0;
    sc[t] = v;
    __syncthreads();
    for (int off = 1; off < 256; off <<= 1) {
        int u = (t >= off) ? sc[t - off] : 0;
        __syncthreads();
        sc[t] += u;
        __syncthreads();
    }
    if (t < NBUCK) {
        int excl = sc[t] - v;
        bbase[t] = excl;
        bcur[t]  = excl;
    }
    if (t == 255) rowptr[N_NODES] = sc[255];
}

// ---- stage 3: per-bucket exclusive scan -> rowptr ----
__global__ void k_s3(const int* __restrict__ deg, const int* __restrict__ bbase,
                     int* __restrict__ rowptr) {
    __shared__ int sc[256];
    int b = blockIdx.x, t = threadIdx.x;
    int idx = b * 256 + t;
    int v = (idx < N_NODES) ? deg[idx] : 0;
    sc[t] = v;
    __syncthreads();
    for (int off = 1; off < 256; off <<= 1) {
        int u = (t >= off) ? sc[t - off] : 0;
        __syncthreads();
        sc[t] += u;
        __syncthreads();
    }
    if (idx < N_NODES) rowptr[idx] = bbase[b] + sc[t] - v;
}

// ---- phase B: partition edges into 196 dst-buckets, packed (src<<8|d&255) ----
#define PART_BLOCKS 256
__global__ void k_part(const int* __restrict__ ei, const int* __restrict__ flags,
                       int* __restrict__ bcur, unsigned int* __restrict__ ebuf) {
    __shared__ int hist[NBUCK];
    __shared__ int base[NBUCK];
    int t = threadIdx.x;
    int i64f = flags[1];
    const int CH = (N_EDGES + PART_BLOCKS - 1) / PART_BLOCKS;  // 6250
    int lo = blockIdx.x * CH;
    int hi = lo + CH; if (hi > N_EDGES) hi = N_EDGES;

    if (t < NBUCK) hist[t] = 0;
    __syncthreads();
    for (int i = lo + t; i < hi; i += 256) {
        int s = ld_edge(ei, i64f, (size_t)i);
        int d = ld_edge(ei, i64f, (size_t)N_EDGES + i);
        if ((unsigned)d < (unsigned)N_NODES && (unsigned)s < (unsigned)N_NODES)
            atomicAdd(&hist[d >> 8], 1);
    }
    __syncthreads();
    if (t < NBUCK) base[t] = (hist[t] > 0) ? atomicAdd(&bcur[t], hist[t]) : 0;
    __syncthreads();
    for (int i = lo + t; i < hi; i += 256) {
        int s = ld_edge(ei, i64f, (size_t)i);
        int d = ld_edge(ei, i64f, (size_t)N_EDGES + i);
        if ((unsigned)d < (unsigned)N_NODES && (unsigned)s < (unsigned)N_NODES) {
            int pos = atomicAdd(&base[d >> 8], 1);
            if ((unsigned)pos < (unsigned)N_EDGES)
                ebuf[pos] = ((unsigned)s << 8) | (unsigned)(d & 255);
        }
    }
}

// ---- phase C: per-bucket local CSR fill (LDS cursors, cache-local writes) ----
__global__ void k_cfill(const unsigned int* __restrict__ ebuf,
                        const int* __restrict__ rowptr, int* __restrict__ col) {
    __shared__ int cur[256];
    int b = blockIdx.x, t = threadIdx.x;
    int nidx = b * 256 + t;
    cur[t] = rowptr[(nidx < N_NODES) ? nidx : N_NODES];
    int e0 = rowptr[b * 256];  // b*256 <= 49920 < N_NODES for b < NBUCK
    int bend = (b + 1) * 256;
    int e1 = rowptr[(bend < N_NODES) ? bend : N_NODES];
    __syncthreads();
    for (int e = e0 + t; e < e1; e += 256) {
        unsigned int v = ebuf[e];
        int dl = (int)(v & 255u);
        int s  = (int)(v >> 8);
        int p = atomicAdd(&cur[dl], 1);
        if ((unsigned)p < (unsigned)N_EDGES) col[p] = s;
    }
}

// ---- W1T[n][k] = bf16(W1[k][n]) ----
__global__ void k_tw1(const void* __restrict__ W1, const int* __restrict__ flags,
                      u16* __restrict__ W1T) {
    int i = blockIdx.x * blockDim.x + threadIdx.x;
    if (i < DIM_IN * DIM_HID) {
        int n = i >> 9;
        int k = i & 511;
        if (flags[0]) W1T[i] = f2bf(((const float*)W1)[k * DIM_HID + n]);
        else          W1T[i] = ((const u16*)W1)[k * DIM_HID + n];
    }
}

// ---- GEMM1 (MFMA 16x16x32 bf16): hs = bf16((x @ W1) * dinv[row]) ----
__launch_bounds__(256)
__global__ void k_gemm1(const void* __restrict__ xraw, const u16* __restrict__ W1T,
                        const int* __restrict__ flags, const float* __restrict__ dinv,
                        u16* __restrict__ hs) {
    int f32f = flags[0];
    int wave = threadIdx.x >> 6;
    int lane = threadIdx.x & 63;
    int m16 = lane & 15;
    int quad = lane >> 4;
    int rbase = blockIdx.x * 64 + wave * 16;
    int ra = rbase + m16;
    if (ra > N_NODES - 1) ra = N_NODES - 1;
    const u16*   xrow_b = (const u16*)xraw   + (size_t)ra * DIM_IN + quad * 8;
    const float* xrow_f = (const float*)xraw + (size_t)ra * DIM_IN + quad * 8;
    const u16* wrow = W1T + (size_t)m16 * DIM_IN + quad * 8;

    f32x4 acc0 = {0.f, 0.f, 0.f, 0.f};
    f32x4 acc1 = {0.f, 0.f, 0.f, 0.f};
    f32x4 acc2 = {0.f, 0.f, 0.f, 0.f};
    f32x4 acc3 = {0.f, 0.f, 0.f, 0.f};

    for (int ks = 0; ks < DIM_IN / 32; ++ks) {
        bf16x8 a;
        if (f32f) {
            const float4* q = reinterpret_cast<const float4*>(xrow_f + ks * 32);
            float4 p0 = q[0], p1 = q[1];
            union { bf16x8 v; u16 s[8]; } u;
            u.s[0] = f2bf(p0.x); u.s[1] = f2bf(p0.y); u.s[2] = f2bf(p0.z); u.s[3] = f2bf(p0.w);
            u.s[4] = f2bf(p1.x); u.s[5] = f2bf(p1.y); u.s[6] = f2bf(p1.z); u.s[7] = f2bf(p1.w);
            a = u.v;
        } else {
            a = *reinterpret_cast<const bf16x8*>(xrow_b + ks * 32);
        }
        bf16x8 b0 = *reinterpret_cast<const bf16x8*>(wrow + ks * 32);
        bf16x8 b1 = *reinterpret_cast<const bf16x8*>(wrow + ks * 32 + 16 * DIM_IN);
        bf16x8 b2 = *reinterpret_cast<const bf16x8*>(wrow + ks * 32 + 32 * DIM_IN);
        bf16x8 b3 = *reinterpret_cast<const bf16x8*>(wrow + ks * 32 + 48 * DIM_IN);
        acc0 = __builtin_amdgcn_mfma_f32_16x16x32_bf16(a, b0, acc0, 0, 0, 0);
        acc1 = __builtin_amdgcn_mfma_f32_16x16x32_bf16(a, b1, acc1, 0, 0, 0);
        acc2 = __builtin_amdgcn_mfma_f32_16x16x32_bf16(a, b2, acc2, 0, 0, 0);
        acc3 = __builtin_amdgcn_mfma_f32_16x16x32_bf16(a, b3, acc3, 0, 0, 0);
    }

#pragma unroll
    for (int i = 0; i < 4; ++i) {
        int r = rbase + quad * 4 + i;
        if (r < N_NODES) {
            float dv = dinv[r];
            u16* orow = hs + (size_t)r * DIM_HID;
            orow[ 0 + m16] = f2bf(acc0[i] * dv);
            orow[16 + m16] = f2bf(acc1[i] * dv);
            orow[32 + m16] = f2bf(acc2[i] * dv);
            orow[48 + m16] = f2bf(acc3[i] * dv);
        }
    }
}

// ---- layer-1 pull aggregation + fused GEMM2 (64->7) ----
__launch_bounds__(256)
__global__ void k_agg1(const u16* __restrict__ hs, const int* __restrict__ rowptr,
                       const int* __restrict__ col, const float* __restrict__ dinv,
                       const void* __restrict__ b1, const void* __restrict__ W2,
                       const int* __restrict__ flags, float* __restrict__ zs) {
    int f32f = flags[0];
    int wave = threadIdx.x >> 6;
    int lane = threadIdx.x & 63;
    int d = blockIdx.x * 4 + wave;
    if (d >= N_NODES) return;
    int start = rowptr[d], end = rowptr[d + 1];
    if (start < 0) start = 0;
    if (end > N_EDGES) end = N_EDGES;
    if (end < start) end = start;

    float acc = 0.f;
    int e = start;
    for (; e + 4 <= end; e += 4) {
        int s0 = col[e], s1 = col[e + 1], s2 = col[e + 2], s3 = col[e + 3];
        float v0 = bf2f(hs[(size_t)s0 * DIM_HID + lane]);
        float v1 = bf2f(hs[(size_t)s1 * DIM_HID + lane]);
        float v2 = bf2f(hs[(size_t)s2 * DIM_HID + lane]);
        float v3 = bf2f(hs[(size_t)s3 * DIM_HID + lane]);
        acc += v0 + v1 + v2 + v3;
    }
    for (; e < end; ++e) acc += bf2f(hs[(size_t)col[e] * DIM_HID + lane]);
    acc += bf2f(hs[(size_t)d * DIM_HID + lane]);

    float b1v = f32f ? ((const float*)b1)[lane] : bf2f(((const u16*)b1)[lane]);
    float dv = dinv[d];
    float h2 = fmaxf(acc * dv + b1v, 0.f);

    float p[7];
#pragma unroll
    for (int f = 0; f < 7; ++f) {
        float w = f32f ? ((const float*)W2)[lane * DIM_OUT + f]
                       : bf2f(((const u16*)W2)[lane * DIM_OUT + f]);
        p[f] = h2 * w;
    }
#pragma unroll
    for (int off = 32; off >= 1; off >>= 1) {
#pragma unroll
        for (int f = 0; f < 7; ++f) p[f] += __shfl_xor(p[f], off);
    }
    if (lane == 0) {
#pragma unroll
        for (int f = 0; f < 7; ++f) zs[(size_t)d * 8 + f] = p[f] * dv;
        zs[(size_t)d * 8 + 7] = 0.f;
    }
}

// ---- layer-2 pull aggregation: out (f32) ----
__launch_bounds__(256)
__global__ void k_agg2(const float* __restrict__ zs, const int* __restrict__ rowptr,
                       const int* __restrict__ col, const float* __restrict__ dinv,
                       const void* __restrict__ b2, const int* __restrict__ flags,
                       float* __restrict__ out) {
    int f32f = flags[0];
    int wave = threadIdx.x >> 6;
    int lane = threadIdx.x & 63;
    int d = blockIdx.x * 4 + wave;
    if (d >= N_NODES) return;
    int f = lane & 7;
    int g = lane >> 3;
    int start = rowptr[d], end = rowptr[d + 1];
    if (start < 0) start = 0;
    if (end > N_EDGES) end = N_EDGES;
    if (end < start) end = start;

    float acc = 0.f;
    for (int e = start + g; e < end; e += 8)
        acc += zs[(size_t)col[e] * 8 + f];

    acc += __shfl_xor(acc, 8);
    acc += __shfl_xor(acc, 16);
    acc += __shfl_xor(acc, 32);

    if (lane < 7) {
        float b2v = f32f ? ((const float*)b2)[lane] : bf2f(((const u16*)b2)[lane]);
        float tot = (acc + zs[(size_t)d * 8 + lane]) * dinv[d] + b2v;
        out[(size_t)d * DIM_OUT + lane] = tot;
    }
}

extern "C" void kernel_launch(void* const* d_in, const int* in_sizes, int n_in,
                              void* d_out, int out_size, void* d_ws, size_t ws_size,
                              hipStream_t stream) {
    const void* x  = d_in[0];
    const int*  ei = (const int*)d_in[1];
    const void* W1 = d_in[2];
    const void* b1 = d_in[3];
    const void* W2 = d_in[4];
    const void* b2 = d_in[5];

    char* ws = (char*)d_ws;
    size_t off = 0;
    auto alloc = [&](size_t bytes) -> void* {
        void* p = ws + off;
        off = (off + bytes + 255) & ~(size_t)255;
        return p;
    };
    int*   flags  = (int*)alloc(32);
    int*   deg    = (int*)alloc((size_t)N_NODES * 4);
    int*   rowptr = (int*)alloc((size_t)(N_NODES + 1) * 4);
    int*   bsum   = (int*)alloc((size_t)NBUCK * 4);
    int*   bbase  = (int*)alloc((size_t)NBUCK * 4);
    int*   bcur   = (int*)alloc((size_t)NBUCK * 4);
    float* dinv   = (float*)alloc((size_t)N_NODES * 4);
    u16*   W1T    = (u16*)alloc((size_t)DIM_IN * DIM_HID * 2);
    unsigned int* ebuf = (unsigned int*)alloc((size_t)N_EDGES * 4);
    int*   colb   = (int*)alloc((size_t)N_EDGES * 4);
    u16*   hs     = (u16*)alloc((size_t)N_NODES * DIM_HID * 2);
    float* zs     = (float*)alloc((size_t)N_NODES * 8 * 4);
    float* out    = (float*)d_out;

    hipMemsetAsync(deg, 0, (size_t)N_NODES * 4, stream);
    k_detect<<<1, 64, 0, stream>>>((const u16*)x, ei, flags);
    k_deg <<<(N_EDGES + 255) / 256, 256, 0, stream>>>(ei, flags, deg);
    k_dinv<<<(N_NODES + 255) / 256, 256, 0, stream>>>(deg, dinv);
    k_s1  <<<NBUCK, 256, 0, stream>>>(deg, bsum);
    k_s2  <<<1, 256, 0, stream>>>(bsum, bbase, bcur, rowptr);
    k_s3  <<<NBUCK, 256, 0, stream>>>(deg, bbase, rowptr);
    k_part<<<PART_BLOCKS, 256, 0, stream>>>(ei, flags, bcur, ebuf);
    k_cfill<<<NBUCK, 256, 0, stream>>>(ebuf, rowptr, colb);
    k_tw1 <<<(DIM_IN * DIM_HID + 255) / 256, 256, 0, stream>>>(W1, flags, W1T);
    k_gemm1<<<(N_NODES + 63) / 64, 256, 0, stream>>>(x, W1T, flags, dinv, hs);
    k_agg1<<<(N_NODES + 3) / 4, 256, 0, stream>>>(hs, rowptr, colb, dinv, b1, W2, flags, zs);
    k_agg2<<<(N_NODES + 3) / 4, 256, 0, stream>>>(zs, rowptr, colb, dinv, b2, flags, out);
}

// Round 8
// 367.458 us; speedup vs baseline: 2.6156x; 1.1473x over previous
//
#include <hip/hip_runtime.h>

#define N_NODES 50000
#define N_EDGES 1600000
#define DIM_IN  512
#define DIM_HID 64
#define DIM_OUT 7
#define NBUCK   196   // ceil(N_NODES/256)
#define PART_BLOCKS 256

using u16 = unsigned short;
using bf16x8 = __attribute__((ext_vector_type(8))) __bf16;
using f32x4  = __attribute__((ext_vector_type(4))) float;

__device__ __forceinline__ float bf2f(u16 u) {
    union { float f; unsigned int i; } v;
    v.i = ((unsigned int)u) << 16;
    return v.f;
}

__device__ __forceinline__ u16 f2bf(float f) {
    union { float f; unsigned int i; } v;
    v.f = f;
    unsigned int r = 0x7FFFu + ((v.i >> 16) & 1u);
    return (u16)((v.i + r) >> 16);
}

// ---- on-device input-encoding detection (proven rounds 2-7) ----
__global__ void k_detect(const u16* __restrict__ xw, const int* __restrict__ ei32,
                         int* __restrict__ flags) {
    if (threadIdx.x == 0 && blockIdx.x == 0) {
        int sane = 0;
        for (int i = 0; i < 256; ++i) {
            u16 w = xw[2 * i];
            int e = (w >> 7) & 0xFF;
            if (e >= 100 && e <= 140) sane++;
        }
        flags[0] = (sane >= 200) ? 0 : 1;
        int nz = 0;
        for (int i = 0; i < 256; ++i)
            if (ei32[2 * i + 1] != 0) nz++;
        flags[1] = (nz == 0) ? 1 : 0;
    }
}

__device__ __forceinline__ int ld_edge(const int* ei, int i64f, size_t idx) {
    if (i64f) return (int)((const long long*)ei)[idx];
    return ei[idx];
}

// ---- bucket-count pass: LDS histogram of d>>8, one global atomic per bucket/block ----
__global__ void k_count(const int* __restrict__ ei, const int* __restrict__ flags,
                        int* __restrict__ gbsum) {
    __shared__ int hist[NBUCK];
    int t = threadIdx.x;
    int i64f = flags[1];
    const int CH = (N_EDGES + PART_BLOCKS - 1) / PART_BLOCKS;  // 6250
    int lo = blockIdx.x * CH;
    int hi = lo + CH; if (hi > N_EDGES) hi = N_EDGES;
    if (t < NBUCK) hist[t] = 0;
    __syncthreads();
    for (int i = lo + t; i < hi; i += 256) {
        int s = ld_edge(ei, i64f, (size_t)i);
        int d = ld_edge(ei, i64f, (size_t)N_EDGES + i);
        if ((unsigned)d < (unsigned)N_NODES && (unsigned)s < (unsigned)N_NODES)
            atomicAdd(&hist[d >> 8], 1);
    }
    __syncthreads();
    if (t < NBUCK && hist[t] > 0) atomicAdd(&gbsum[t], hist[t]);
}

// ---- exclusive scan of bucket sums -> bbase + bucket cursor ----
__global__ void k_s2(const int* __restrict__ gbsum, int* __restrict__ bbase,
                     int* __restrict__ bcur, int* __restrict__ rowptr) {
    __shared__ int sc[256];
    int t = threadIdx.x;
    int v = (t < NBUCK) ? gbsum[t] : 0;
    sc[t] = v;
    __syncthreads();
    for (int off = 1; off < 256; off <<= 1) {
        int u = (t >= off) ? sc[t - off] : 0;
        __syncthreads();
        sc[t] += u;
        __syncthreads();
    }
    if (t < NBUCK) {
        int excl = sc[t] - v;
        bbase[t] = excl;
        bcur[t]  = excl;
    }
    if (t == 255) rowptr[N_NODES] = sc[255];
}

// ---- partition edges into 196 dst-buckets, packed (src<<8|d&255) ----
__global__ void k_part(const int* __restrict__ ei, const int* __restrict__ flags,
                       int* __restrict__ bcur, unsigned int* __restrict__ ebuf) {
    __shared__ int hist[NBUCK];
    __shared__ int base[NBUCK];
    int t = threadIdx.x;
    int i64f = flags[1];
    const int CH = (N_EDGES + PART_BLOCKS - 1) / PART_BLOCKS;
    int lo = blockIdx.x * CH;
    int hi = lo + CH; if (hi > N_EDGES) hi = N_EDGES;

    if (t < NBUCK) hist[t] = 0;
    __syncthreads();
    for (int i = lo + t; i < hi; i += 256) {
        int s = ld_edge(ei, i64f, (size_t)i);
        int d = ld_edge(ei, i64f, (size_t)N_EDGES + i);
        if ((unsigned)d < (unsigned)N_NODES && (unsigned)s < (unsigned)N_NODES)
            atomicAdd(&hist[d >> 8], 1);
    }
    __syncthreads();
    if (t < NBUCK) base[t] = (hist[t] > 0) ? atomicAdd(&bcur[t], hist[t]) : 0;
    __syncthreads();
    for (int i = lo + t; i < hi; i += 256) {
        int s = ld_edge(ei, i64f, (size_t)i);
        int d = ld_edge(ei, i64f, (size_t)N_EDGES + i);
        if ((unsigned)d < (unsigned)N_NODES && (unsigned)s < (unsigned)N_NODES) {
            int pos = atomicAdd(&base[d >> 8], 1);
            if ((unsigned)pos < (unsigned)N_EDGES)
                ebuf[pos] = ((unsigned)s << 8) | (unsigned)(d & 255);
        }
    }
}

// ---- per-bucket: LDS degree histogram -> rowptr + dinv + CSR fill ----
__global__ void k_cfill(const unsigned int* __restrict__ ebuf,
                        const int* __restrict__ bbase, const int* __restrict__ gbsum,
                        int* __restrict__ rowptr, float* __restrict__ dinv,
                        int* __restrict__ col) {
    __shared__ int dcnt[256];
    __shared__ int sc[256];
    __shared__ int cur[256];
    int b = blockIdx.x, t = threadIdx.x;
    int e0 = bbase[b];
    int e1 = e0 + gbsum[b];
    dcnt[t] = 0;
    __syncthreads();
    for (int e = e0 + t; e < e1; e += 256)
        atomicAdd(&dcnt[ebuf[e] & 255u], 1);
    __syncthreads();
    int v = dcnt[t];
    sc[t] = v;
    __syncthreads();
    for (int off = 1; off < 256; off <<= 1) {
        int u = (t >= off) ? sc[t - off] : 0;
        __syncthreads();
        sc[t] += u;
        __syncthreads();
    }
    int row0 = e0 + sc[t] - v;   // global CSR start for node b*256+t
    cur[t] = row0;
    int idx = b * 256 + t;
    if (idx < N_NODES) {
        rowptr[idx] = row0;
        dinv[idx] = rsqrtf((float)(v + 1));  // +1 self-loop
    }
    __syncthreads();
    for (int e = e0 + t; e < e1; e += 256) {
        unsigned int x = ebuf[e];
        int p = atomicAdd(&cur[x & 255u], 1);
        if ((unsigned)p < (unsigned)N_EDGES) col[p] = (int)(x >> 8);
    }
}

// ---- W1T[n][k] = bf16(W1[k][n]) ----
__global__ void k_tw1(const void* __restrict__ W1, const int* __restrict__ flags,
                      u16* __restrict__ W1T) {
    int i = blockIdx.x * blockDim.x + threadIdx.x;
    if (i < DIM_IN * DIM_HID) {
        int n = i >> 9;
        int k = i & 511;
        if (flags[0]) W1T[i] = f2bf(((const float*)W1)[k * DIM_HID + n]);
        else          W1T[i] = ((const u16*)W1)[k * DIM_HID + n];
    }
}

// ---- GEMM1 (MFMA 16x16x32 bf16): hs = bf16((x @ W1) * dinv[row]) ----
__launch_bounds__(256)
__global__ void k_gemm1(const void* __restrict__ xraw, const u16* __restrict__ W1T,
                        const int* __restrict__ flags, const float* __restrict__ dinv,
                        u16* __restrict__ hs) {
    int f32f = flags[0];
    int wave = threadIdx.x >> 6;
    int lane = threadIdx.x & 63;
    int m16 = lane & 15;
    int quad = lane >> 4;
    int rbase = blockIdx.x * 64 + wave * 16;
    int ra = rbase + m16;
    if (ra > N_NODES - 1) ra = N_NODES - 1;
    const u16*   xrow_b = (const u16*)xraw   + (size_t)ra * DIM_IN + quad * 8;
    const float* xrow_f = (const float*)xraw + (size_t)ra * DIM_IN + quad * 8;
    const u16* wrow = W1T + (size_t)m16 * DIM_IN + quad * 8;

    f32x4 acc0 = {0.f, 0.f, 0.f, 0.f};
    f32x4 acc1 = {0.f, 0.f, 0.f, 0.f};
    f32x4 acc2 = {0.f, 0.f, 0.f, 0.f};
    f32x4 acc3 = {0.f, 0.f, 0.f, 0.f};

    for (int ks = 0; ks < DIM_IN / 32; ++ks) {
        bf16x8 a;
        if (f32f) {
            const float4* q = reinterpret_cast<const float4*>(xrow_f + ks * 32);
            float4 p0 = q[0], p1 = q[1];
            union { bf16x8 v; u16 s[8]; } u;
            u.s[0] = f2bf(p0.x); u.s[1] = f2bf(p0.y); u.s[2] = f2bf(p0.z); u.s[3] = f2bf(p0.w);
            u.s[4] = f2bf(p1.x); u.s[5] = f2bf(p1.y); u.s[6] = f2bf(p1.z); u.s[7] = f2bf(p1.w);
            a = u.v;
        } else {
            a = *reinterpret_cast<const bf16x8*>(xrow_b + ks * 32);
        }
        bf16x8 b0 = *reinterpret_cast<const bf16x8*>(wrow + ks * 32);
        bf16x8 b1 = *reinterpret_cast<const bf16x8*>(wrow + ks * 32 + 16 * DIM_IN);
        bf16x8 b2 = *reinterpret_cast<const bf16x8*>(wrow + ks * 32 + 32 * DIM_IN);
        bf16x8 b3 = *reinterpret_cast<const bf16x8*>(wrow + ks * 32 + 48 * DIM_IN);
        acc0 = __builtin_amdgcn_mfma_f32_16x16x32_bf16(a, b0, acc0, 0, 0, 0);
        acc1 = __builtin_amdgcn_mfma_f32_16x16x32_bf16(a, b1, acc1, 0, 0, 0);
        acc2 = __builtin_amdgcn_mfma_f32_16x16x32_bf16(a, b2, acc2, 0, 0, 0);
        acc3 = __builtin_amdgcn_mfma_f32_16x16x32_bf16(a, b3, acc3, 0, 0, 0);
    }

#pragma unroll
    for (int i = 0; i < 4; ++i) {
        int r = rbase + quad * 4 + i;
        if (r < N_NODES) {
            float dv = dinv[r];
            u16* orow = hs + (size_t)r * DIM_HID;
            orow[ 0 + m16] = f2bf(acc0[i] * dv);
            orow[16 + m16] = f2bf(acc1[i] * dv);
            orow[32 + m16] = f2bf(acc2[i] * dv);
            orow[48 + m16] = f2bf(acc3[i] * dv);
        }
    }
}

// ---- layer-1 pull aggregation + fused GEMM2 (64->7) ----
__launch_bounds__(256)
__global__ void k_agg1(const u16* __restrict__ hs, const int* __restrict__ rowptr,
                       const int* __restrict__ col, const float* __restrict__ dinv,
                       const void* __restrict__ b1, const void* __restrict__ W2,
                       const int* __restrict__ flags, float* __restrict__ zs) {
    int f32f = flags[0];
    int wave = threadIdx.x >> 6;
    int lane = threadIdx.x & 63;
    int d = blockIdx.x * 4 + wave;
    if (d >= N_NODES) return;
    int start = rowptr[d], end = rowptr[d + 1];
    if (start < 0) start = 0;
    if (end > N_EDGES) end = N_EDGES;
    if (end < start) end = start;

    float acc = 0.f;
    int e = start;
    for (; e + 4 <= end; e += 4) {
        int s0 = col[e], s1 = col[e + 1], s2 = col[e + 2], s3 = col[e + 3];
        float v0 = bf2f(hs[(size_t)s0 * DIM_HID + lane]);
        float v1 = bf2f(hs[(size_t)s1 * DIM_HID + lane]);
        float v2 = bf2f(hs[(size_t)s2 * DIM_HID + lane]);
        float v3 = bf2f(hs[(size_t)s3 * DIM_HID + lane]);
        acc += v0 + v1 + v2 + v3;
    }
    for (; e < end; ++e) acc += bf2f(hs[(size_t)col[e] * DIM_HID + lane]);
    acc += bf2f(hs[(size_t)d * DIM_HID + lane]);

    float b1v = f32f ? ((const float*)b1)[lane] : bf2f(((const u16*)b1)[lane]);
    float dv = dinv[d];
    float h2 = fmaxf(acc * dv + b1v, 0.f);

    float p[7];
#pragma unroll
    for (int f = 0; f < 7; ++f) {
        float w = f32f ? ((const float*)W2)[lane * DIM_OUT + f]
                       : bf2f(((const u16*)W2)[lane * DIM_OUT + f]);
        p[f] = h2 * w;
    }
#pragma unroll
    for (int off = 32; off >= 1; off >>= 1) {
#pragma unroll
        for (int f = 0; f < 7; ++f) p[f] += __shfl_xor(p[f], off);
    }
    if (lane == 0) {
#pragma unroll
        for (int f = 0; f < 7; ++f) zs[(size_t)d * 8 + f] = p[f] * dv;
        zs[(size_t)d * 8 + 7] = 0.f;
    }
}

// ---- layer-2 pull aggregation: out (f32) ----
__launch_bounds__(256)
__global__ void k_agg2(const float* __restrict__ zs, const int* __restrict__ rowptr,
                       const int* __restrict__ col, const float* __restrict__ dinv,
                       const void* __restrict__ b2, const int* __restrict__ flags,
                       float* __restrict__ out) {
    int f32f = flags[0];
    int wave = threadIdx.x >> 6;
    int lane = threadIdx.x & 63;
    int d = blockIdx.x * 4 + wave;
    if (d >= N_NODES) return;
    int f = lane & 7;
    int g = lane >> 3;
    int start = rowptr[d], end = rowptr[d + 1];
    if (start < 0) start = 0;
    if (end > N_EDGES) end = N_EDGES;
    if (end < start) end = start;

    float acc = 0.f;
    for (int e = start + g; e < end; e += 8)
        acc += zs[(size_t)col[e] * 8 + f];

    acc += __shfl_xor(acc, 8);
    acc += __shfl_xor(acc, 16);
    acc += __shfl_xor(acc, 32);

    if (lane < 7) {
        float b2v = f32f ? ((const float*)b2)[lane] : bf2f(((const u16*)b2)[lane]);
        float tot = (acc + zs[(size_t)d * 8 + lane]) * dinv[d] + b2v;
        out[(size_t)d * DIM_OUT + lane] = tot;
    }
}

extern "C" void kernel_launch(void* const* d_in, const int* in_sizes, int n_in,
                              void* d_out, int out_size, void* d_ws, size_t ws_size,
                              hipStream_t stream) {
    const void* x  = d_in[0];
    const int*  ei = (const int*)d_in[1];
    const void* W1 = d_in[2];
    const void* b1 = d_in[3];
    const void* W2 = d_in[4];
    const void* b2 = d_in[5];

    char* ws = (char*)d_ws;
    size_t off = 0;
    auto alloc = [&](size_t bytes) -> void* {
        void* p = ws + off;
        off = (off + bytes + 255) & ~(size_t)255;
        return p;
    };
    int*   flags  = (int*)alloc(32);
    int*   rowptr = (int*)alloc((size_t)(N_NODES + 1) * 4);
    int*   gbsum  = (int*)alloc((size_t)NBUCK * 4);
    int*   bbase  = (int*)alloc((size_t)NBUCK * 4);
    int*   bcur   = (int*)alloc((size_t)NBUCK * 4);
    float* dinv   = (float*)alloc((size_t)N_NODES * 4);
    u16*   W1T    = (u16*)alloc((size_t)DIM_IN * DIM_HID * 2);
    unsigned int* ebuf = (unsigned int*)alloc((size_t)N_EDGES * 4);
    int*   colb   = (int*)alloc((size_t)N_EDGES * 4);
    u16*   hs     = (u16*)alloc((size_t)N_NODES * DIM_HID * 2);
    float* zs     = (float*)alloc((size_t)N_NODES * 8 * 4);
    float* out    = (float*)d_out;

    hipMemsetAsync(gbsum, 0, (size_t)NBUCK * 4, stream);
    k_detect<<<1, 64, 0, stream>>>((const u16*)x, ei, flags);
    k_count<<<PART_BLOCKS, 256, 0, stream>>>(ei, flags, gbsum);
    k_s2   <<<1, 256, 0, stream>>>(gbsum, bbase, bcur, rowptr);
    k_part <<<PART_BLOCKS, 256, 0, stream>>>(ei, flags, bcur, ebuf);
    k_cfill<<<NBUCK, 256, 0, stream>>>(ebuf, bbase, gbsum, rowptr, dinv, colb);
    k_tw1  <<<(DIM_IN * DIM_HID + 255) / 256, 256, 0, stream>>>(W1, flags, W1T);
    k_gemm1<<<(N_NODES + 63) / 64, 256, 0, stream>>>(x, W1T, flags, dinv, hs);
    k_agg1 <<<(N_NODES + 3) / 4, 256, 0, stream>>>(hs, rowptr, colb, dinv, b1, W2, flags, zs);
    k_agg2 <<<(N_NODES + 3) / 4, 256, 0, stream>>>(zs, rowptr, colb, dinv, b2, flags, out);
}

// Round 9
// 367.191 us; speedup vs baseline: 2.6175x; 1.0007x over previous
//
#include <hip/hip_runtime.h>

#define N_NODES 50000
#define N_EDGES 1600000
#define DIM_IN  512
#define DIM_HID 64
#define DIM_OUT 7
#define NBUCK   196          // ceil(N_NODES/256) dst buckets
#define SRC_SHIFT 13         // src tile = 8192 nodes (1 MB of hs)
#define NTILE   7            // ceil(50000/8192)
#define NBIN    (NBUCK * NTILE)   // 1372 two-level bins
#define PART_BLOCKS 256

using u16 = unsigned short;
using bf16x8 = __attribute__((ext_vector_type(8))) __bf16;
using f32x4  = __attribute__((ext_vector_type(4))) float;

__device__ __forceinline__ float bf2f(u16 u) {
    union { float f; unsigned int i; } v;
    v.i = ((unsigned int)u) << 16;
    return v.f;
}

__device__ __forceinline__ u16 f2bf(float f) {
    union { float f; unsigned int i; } v;
    v.f = f;
    unsigned int r = 0x7FFFu + ((v.i >> 16) & 1u);
    return (u16)((v.i + r) >> 16);
}

// ---- on-device input-encoding detection (proven rounds 2-8) ----
__global__ void k_detect(const u16* __restrict__ xw, const int* __restrict__ ei32,
                         int* __restrict__ flags) {
    if (threadIdx.x == 0 && blockIdx.x == 0) {
        int sane = 0;
        for (int i = 0; i < 256; ++i) {
            u16 w = xw[2 * i];
            int e = (w >> 7) & 0xFF;
            if (e >= 100 && e <= 140) sane++;
        }
        flags[0] = (sane >= 200) ? 0 : 1;
        int nz = 0;
        for (int i = 0; i < 256; ++i)
            if (ei32[2 * i + 1] != 0) nz++;
        flags[1] = (nz == 0) ? 1 : 0;
    }
}

__device__ __forceinline__ int ld_edge(const int* ei, int i64f, size_t idx) {
    if (i64f) return (int)((const long long*)ei)[idx];
    return ei[idx];
}

// two-level bin: (dst bucket, src tile)
__device__ __forceinline__ int edge_bin(int s, int d) {
    return (d >> 8) * NTILE + (s >> SRC_SHIFT);
}

// ---- bin-count pass: LDS histogram, one global atomic per bin/block ----
__global__ void k_count(const int* __restrict__ ei, const int* __restrict__ flags,
                        int* __restrict__ gbsum) {
    __shared__ int hist[NBIN];
    int t = threadIdx.x;
    int i64f = flags[1];
    const int CH = (N_EDGES + PART_BLOCKS - 1) / PART_BLOCKS;  // 6250
    int lo = blockIdx.x * CH;
    int hi = lo + CH; if (hi > N_EDGES) hi = N_EDGES;
    for (int j = t; j < NBIN; j += 256) hist[j] = 0;
    __syncthreads();
    for (int i = lo + t; i < hi; i += 256) {
        int s = ld_edge(ei, i64f, (size_t)i);
        int d = ld_edge(ei, i64f, (size_t)N_EDGES + i);
        if ((unsigned)d < (unsigned)N_NODES && (unsigned)s < (unsigned)N_NODES)
            atomicAdd(&hist[edge_bin(s, d)], 1);
    }
    __syncthreads();
    for (int j = t; j < NBIN; j += 256)
        if (hist[j] > 0) atomicAdd(&gbsum[j], hist[j]);
}

// ---- exclusive scan of NBIN bin sums -> bbase + bin cursor ----
__global__ void k_s2(const int* __restrict__ gbsum, int* __restrict__ bbase,
                     int* __restrict__ bcur, int* __restrict__ rowptr) {
    __shared__ int sc[256];
    const int CPB = (NBIN + 255) / 256;  // 6 bins per thread
    int t = threadIdx.x;
    int base = t * CPB;
    int s = 0;
    for (int i = 0; i < CPB; ++i) {
        int idx = base + i;
        if (idx < NBIN) s += gbsum[idx];
    }
    sc[t] = s;
    __syncthreads();
    for (int off = 1; off < 256; off <<= 1) {
        int u = (t >= off) ? sc[t - off] : 0;
        __syncthreads();
        sc[t] += u;
        __syncthreads();
    }
    int run = sc[t] - s;  // exclusive prefix of this thread's chunk
    for (int i = 0; i < CPB; ++i) {
        int idx = base + i;
        if (idx < NBIN) {
            bbase[idx] = run;
            bcur[idx]  = run;
            run += gbsum[idx];
        }
    }
    if (t == 255) rowptr[N_NODES] = sc[255];
}

// ---- partition edges into 1372 (dst-bucket, src-tile) bins, packed (src<<8|d&255) ----
__global__ void k_part(const int* __restrict__ ei, const int* __restrict__ flags,
                       int* __restrict__ bcur, unsigned int* __restrict__ ebuf) {
    __shared__ int hist[NBIN];
    __shared__ int base[NBIN];
    int t = threadIdx.x;
    int i64f = flags[1];
    const int CH = (N_EDGES + PART_BLOCKS - 1) / PART_BLOCKS;
    int lo = blockIdx.x * CH;
    int hi = lo + CH; if (hi > N_EDGES) hi = N_EDGES;

    for (int j = t; j < NBIN; j += 256) hist[j] = 0;
    __syncthreads();
    for (int i = lo + t; i < hi; i += 256) {
        int s = ld_edge(ei, i64f, (size_t)i);
        int d = ld_edge(ei, i64f, (size_t)N_EDGES + i);
        if ((unsigned)d < (unsigned)N_NODES && (unsigned)s < (unsigned)N_NODES)
            atomicAdd(&hist[edge_bin(s, d)], 1);
    }
    __syncthreads();
    for (int j = t; j < NBIN; j += 256)
        base[j] = (hist[j] > 0) ? atomicAdd(&bcur[j], hist[j]) : 0;
    __syncthreads();
    for (int i = lo + t; i < hi; i += 256) {
        int s = ld_edge(ei, i64f, (size_t)i);
        int d = ld_edge(ei, i64f, (size_t)N_EDGES + i);
        if ((unsigned)d < (unsigned)N_NODES && (unsigned)s < (unsigned)N_NODES) {
            int pos = atomicAdd(&base[edge_bin(s, d)], 1);
            if ((unsigned)pos < (unsigned)N_EDGES)
                ebuf[pos] = ((unsigned)s << 8) | (unsigned)(d & 255);
        }
    }
}

// ---- per-bucket: LDS degree histogram -> rowptr + dinv + CSR fill ----
// bucket b's edges = bins [b*NTILE, (b+1)*NTILE), contiguous & src-tile-ordered
__global__ void k_cfill(const unsigned int* __restrict__ ebuf,
                        const int* __restrict__ bbase, const int* __restrict__ rowptrN,
                        int* __restrict__ rowptr, float* __restrict__ dinv,
                        int* __restrict__ col) {
    __shared__ int dcnt[256];
    __shared__ int sc[256];
    __shared__ int cur[256];
    int b = blockIdx.x, t = threadIdx.x;
    int e0 = bbase[b * NTILE];
    int e1 = (b == NBUCK - 1) ? rowptrN[N_NODES] : bbase[(b + 1) * NTILE];
    dcnt[t] = 0;
    __syncthreads();
    for (int e = e0 + t; e < e1; e += 256)
        atomicAdd(&dcnt[ebuf[e] & 255u], 1);
    __syncthreads();
    int v = dcnt[t];
    sc[t] = v;
    __syncthreads();
    for (int off = 1; off < 256; off <<= 1) {
        int u = (t >= off) ? sc[t - off] : 0;
        __syncthreads();
        sc[t] += u;
        __syncthreads();
    }
    int row0 = e0 + sc[t] - v;
    cur[t] = row0;
    int idx = b * 256 + t;
    if (idx < N_NODES) {
        rowptr[idx] = row0;
        dinv[idx] = rsqrtf((float)(v + 1));  // +1 self-loop
    }
    __syncthreads();
    // strided sweep preserves src-tile grouping per node's list (256-edge fuzz)
    for (int e = e0 + t; e < e1; e += 256) {
        unsigned int x = ebuf[e];
        int p = atomicAdd(&cur[x & 255u], 1);
        if ((unsigned)p < (unsigned)N_EDGES) col[p] = (int)(x >> 8);
    }
}

// ---- W1T[n][k] = bf16(W1[k][n]) ----
__global__ void k_tw1(const void* __restrict__ W1, const int* __restrict__ flags,
                      u16* __restrict__ W1T) {
    int i = blockIdx.x * blockDim.x + threadIdx.x;
    if (i < DIM_IN * DIM_HID) {
        int n = i >> 9;
        int k = i & 511;
        if (flags[0]) W1T[i] = f2bf(((const float*)W1)[k * DIM_HID + n]);
        else          W1T[i] = ((const u16*)W1)[k * DIM_HID + n];
    }
}

// ---- GEMM1 (MFMA 16x16x32 bf16): hs = bf16((x @ W1) * dinv[row]) ----
__launch_bounds__(256)
__global__ void k_gemm1(const void* __restrict__ xraw, const u16* __restrict__ W1T,
                        const int* __restrict__ flags, const float* __restrict__ dinv,
                        u16* __restrict__ hs) {
    int f32f = flags[0];
    int wave = threadIdx.x >> 6;
    int lane = threadIdx.x & 63;
    int m16 = lane & 15;
    int quad = lane >> 4;
    int rbase = blockIdx.x * 64 + wave * 16;
    int ra = rbase + m16;
    if (ra > N_NODES - 1) ra = N_NODES - 1;
    const u16*   xrow_b = (const u16*)xraw   + (size_t)ra * DIM_IN + quad * 8;
    const float* xrow_f = (const float*)xraw + (size_t)ra * DIM_IN + quad * 8;
    const u16* wrow = W1T + (size_t)m16 * DIM_IN + quad * 8;

    f32x4 acc0 = {0.f, 0.f, 0.f, 0.f};
    f32x4 acc1 = {0.f, 0.f, 0.f, 0.f};
    f32x4 acc2 = {0.f, 0.f, 0.f, 0.f};
    f32x4 acc3 = {0.f, 0.f, 0.f, 0.f};

    for (int ks = 0; ks < DIM_IN / 32; ++ks) {
        bf16x8 a;
        if (f32f) {
            const float4* q = reinterpret_cast<const float4*>(xrow_f + ks * 32);
            float4 p0 = q[0], p1 = q[1];
            union { bf16x8 v; u16 s[8]; } u;
            u.s[0] = f2bf(p0.x); u.s[1] = f2bf(p0.y); u.s[2] = f2bf(p0.z); u.s[3] = f2bf(p0.w);
            u.s[4] = f2bf(p1.x); u.s[5] = f2bf(p1.y); u.s[6] = f2bf(p1.z); u.s[7] = f2bf(p1.w);
            a = u.v;
        } else {
            a = *reinterpret_cast<const bf16x8*>(xrow_b + ks * 32);
        }
        bf16x8 b0 = *reinterpret_cast<const bf16x8*>(wrow + ks * 32);
        bf16x8 b1 = *reinterpret_cast<const bf16x8*>(wrow + ks * 32 + 16 * DIM_IN);
        bf16x8 b2 = *reinterpret_cast<const bf16x8*>(wrow + ks * 32 + 32 * DIM_IN);
        bf16x8 b3 = *reinterpret_cast<const bf16x8*>(wrow + ks * 32 + 48 * DIM_IN);
        acc0 = __builtin_amdgcn_mfma_f32_16x16x32_bf16(a, b0, acc0, 0, 0, 0);
        acc1 = __builtin_amdgcn_mfma_f32_16x16x32_bf16(a, b1, acc1, 0, 0, 0);
        acc2 = __builtin_amdgcn_mfma_f32_16x16x32_bf16(a, b2, acc2, 0, 0, 0);
        acc3 = __builtin_amdgcn_mfma_f32_16x16x32_bf16(a, b3, acc3, 0, 0, 0);
    }

#pragma unroll
    for (int i = 0; i < 4; ++i) {
        int r = rbase + quad * 4 + i;
        if (r < N_NODES) {
            float dv = dinv[r];
            u16* orow = hs + (size_t)r * DIM_HID;
            orow[ 0 + m16] = f2bf(acc0[i] * dv);
            orow[16 + m16] = f2bf(acc1[i] * dv);
            orow[32 + m16] = f2bf(acc2[i] * dv);
            orow[48 + m16] = f2bf(acc3[i] * dv);
        }
    }
}

// ---- layer-1 pull aggregation + fused GEMM2 (64->7) ----
__launch_bounds__(256)
__global__ void k_agg1(const u16* __restrict__ hs, const int* __restrict__ rowptr,
                       const int* __restrict__ col, const float* __restrict__ dinv,
                       const void* __restrict__ b1, const void* __restrict__ W2,
                       const int* __restrict__ flags, float* __restrict__ zs) {
    int f32f = flags[0];
    int wave = threadIdx.x >> 6;
    int lane = threadIdx.x & 63;
    int d = blockIdx.x * 4 + wave;
    if (d >= N_NODES) return;
    int start = rowptr[d], end = rowptr[d + 1];
    if (start < 0) start = 0;
    if (end > N_EDGES) end = N_EDGES;
    if (end < start) end = start;

    float acc = 0.f;
    int e = start;
    for (; e + 4 <= end; e += 4) {
        int s0 = col[e], s1 = col[e + 1], s2 = col[e + 2], s3 = col[e + 3];
        float v0 = bf2f(hs[(size_t)s0 * DIM_HID + lane]);
        float v1 = bf2f(hs[(size_t)s1 * DIM_HID + lane]);
        float v2 = bf2f(hs[(size_t)s2 * DIM_HID + lane]);
        float v3 = bf2f(hs[(size_t)s3 * DIM_HID + lane]);
        acc += v0 + v1 + v2 + v3;
    }
    for (; e < end; ++e) acc += bf2f(hs[(size_t)col[e] * DIM_HID + lane]);
    acc += bf2f(hs[(size_t)d * DIM_HID + lane]);

    float b1v = f32f ? ((const float*)b1)[lane] : bf2f(((const u16*)b1)[lane]);
    float dv = dinv[d];
    float h2 = fmaxf(acc * dv + b1v, 0.f);

    float p[7];
#pragma unroll
    for (int f = 0; f < 7; ++f) {
        float w = f32f ? ((const float*)W2)[lane * DIM_OUT + f]
                       : bf2f(((const u16*)W2)[lane * DIM_OUT + f]);
        p[f] = h2 * w;
    }
#pragma unroll
    for (int off = 32; off >= 1; off >>= 1) {
#pragma unroll
        for (int f = 0; f < 7; ++f) p[f] += __shfl_xor(p[f], off);
    }
    if (lane == 0) {
#pragma unroll
        for (int f = 0; f < 7; ++f) zs[(size_t)d * 8 + f] = p[f] * dv;
        zs[(size_t)d * 8 + 7] = 0.f;
    }
}

// ---- layer-2 pull aggregation: out (f32) ----
__launch_bounds__(256)
__global__ void k_agg2(const float* __restrict__ zs, const int* __restrict__ rowptr,
                       const int* __restrict__ col, const float* __restrict__ dinv,
                       const void* __restrict__ b2, const int* __restrict__ flags,
                       float* __restrict__ out) {
    int f32f = flags[0];
    int wave = threadIdx.x >> 6;
    int lane = threadIdx.x & 63;
    int d = blockIdx.x * 4 + wave;
    if (d >= N_NODES) return;
    int f = lane & 7;
    int g = lane >> 3;
    int start = rowptr[d], end = rowptr[d + 1];
    if (start < 0) start = 0;
    if (end > N_EDGES) end = N_EDGES;
    if (end < start) end = start;

    float acc = 0.f;
    for (int e = start + g; e < end; e += 8)
        acc += zs[(size_t)col[e] * 8 + f];

    acc += __shfl_xor(acc, 8);
    acc += __shfl_xor(acc, 16);
    acc += __shfl_xor(acc, 32);

    if (lane < 7) {
        float b2v = f32f ? ((const float*)b2)[lane] : bf2f(((const u16*)b2)[lane]);
        float tot = (acc + zs[(size_t)d * 8 + lane]) * dinv[d] + b2v;
        out[(size_t)d * DIM_OUT + lane] = tot;
    }
}

extern "C" void kernel_launch(void* const* d_in, const int* in_sizes, int n_in,
                              void* d_out, int out_size, void* d_ws, size_t ws_size,
                              hipStream_t stream) {
    const void* x  = d_in[0];
    const int*  ei = (const int*)d_in[1];
    const void* W1 = d_in[2];
    const void* b1 = d_in[3];
    const void* W2 = d_in[4];
    const void* b2 = d_in[5];

    char* ws = (char*)d_ws;
    size_t off = 0;
    auto alloc = [&](size_t bytes) -> void* {
        void* p = ws + off;
        off = (off + bytes + 255) & ~(size_t)255;
        return p;
    };
    int*   flags  = (int*)alloc(32);
    int*   rowptr = (int*)alloc((size_t)(N_NODES + 1) * 4);
    int*   gbsum  = (int*)alloc((size_t)NBIN * 4);
    int*   bbase  = (int*)alloc((size_t)NBIN * 4);
    int*   bcur   = (int*)alloc((size_t)NBIN * 4);
    float* dinv   = (float*)alloc((size_t)N_NODES * 4);
    u16*   W1T    = (u16*)alloc((size_t)DIM_IN * DIM_HID * 2);
    unsigned int* ebuf = (unsigned int*)alloc((size_t)N_EDGES * 4);
    int*   colb   = (int*)alloc((size_t)N_EDGES * 4);
    u16*   hs     = (u16*)alloc((size_t)N_NODES * DIM_HID * 2);
    float* zs     = (float*)alloc((size_t)N_NODES * 8 * 4);
    float* out    = (float*)d_out;

    hipMemsetAsync(gbsum, 0, (size_t)NBIN * 4, stream);
    k_detect<<<1, 64, 0, stream>>>((const u16*)x, ei, flags);
    k_count<<<PART_BLOCKS, 256, 0, stream>>>(ei, flags, gbsum);
    k_s2   <<<1, 256, 0, stream>>>(gbsum, bbase, bcur, rowptr);
    k_part <<<PART_BLOCKS, 256, 0, stream>>>(ei, flags, bcur, ebuf);
    k_cfill<<<NBUCK, 256, 0, stream>>>(ebuf, bbase, rowptr, rowptr, dinv, colb);
    k_tw1  <<<(DIM_IN * DIM_HID + 255) / 256, 256, 0, stream>>>(W1, flags, W1T);
    k_gemm1<<<(N_NODES + 63) / 64, 256, 0, stream>>>(x, W1T, flags, dinv, hs);
    k_agg1 <<<(N_NODES + 3) / 4, 256, 0, stream>>>(hs, rowptr, colb, dinv, b1, W2, flags, zs);
    k_agg2 <<<(N_NODES + 3) / 4, 256, 0, stream>>>(zs, rowptr, colb, dinv, b2, flags, out);
}

// Round 10
// 348.072 us; speedup vs baseline: 2.7613x; 1.0549x over previous
//
#include <hip/hip_runtime.h>

#define N_NODES 50000
#define N_EDGES 1600000
#define DIM_IN  512
#define DIM_HID 64
#define DIM_OUT 7
#define NBUCK   196          // ceil(N_NODES/256) dst buckets
#define PART_BLOCKS 256

using u16 = unsigned short;
using bf16x8 = __attribute__((ext_vector_type(8))) __bf16;
using f32x4  = __attribute__((ext_vector_type(4))) float;

__device__ __forceinline__ float bf2f(u16 u) {
    union { float f; unsigned int i; } v;
    v.i = ((unsigned int)u) << 16;
    return v.f;
}

__device__ __forceinline__ u16 f2bf(float f) {
    union { float f; unsigned int i; } v;
    v.f = f;
    unsigned int r = 0x7FFFu + ((v.i >> 16) & 1u);
    return (u16)((v.i + r) >> 16);
}

// ---- on-device input-encoding detection (proven rounds 2-9) ----
__global__ void k_detect(const u16* __restrict__ xw, const int* __restrict__ ei32,
                         int* __restrict__ flags) {
    if (threadIdx.x == 0 && blockIdx.x == 0) {
        int sane = 0;
        for (int i = 0; i < 256; ++i) {
            u16 w = xw[2 * i];
            int e = (w >> 7) & 0xFF;
            if (e >= 100 && e <= 140) sane++;
        }
        flags[0] = (sane >= 200) ? 0 : 1;
        int nz = 0;
        for (int i = 0; i < 256; ++i)
            if (ei32[2 * i + 1] != 0) nz++;
        flags[1] = (nz == 0) ? 1 : 0;
    }
}

__device__ __forceinline__ int ld_edge(const int* ei, int i64f, size_t idx) {
    if (i64f) return (int)((const long long*)ei)[idx];
    return ei[idx];
}

// ---- pass 1: per-block bin counts -> cnt[bin][block] + global bin sums ----
__global__ void k_count(const int* __restrict__ ei, const int* __restrict__ flags,
                        int* __restrict__ gbsum, int* __restrict__ cnt) {
    __shared__ int hist[NBUCK];
    int t = threadIdx.x;
    int i64f = flags[1];
    const int CH = (N_EDGES + PART_BLOCKS - 1) / PART_BLOCKS;  // 6250
    int lo = blockIdx.x * CH;
    int hi = lo + CH; if (hi > N_EDGES) hi = N_EDGES;
    if (t < NBUCK) hist[t] = 0;
    __syncthreads();
    for (int i = lo + t; i < hi; i += 256) {
        int s = ld_edge(ei, i64f, (size_t)i);
        int d = ld_edge(ei, i64f, (size_t)N_EDGES + i);
        if ((unsigned)d < (unsigned)N_NODES && (unsigned)s < (unsigned)N_NODES)
            atomicAdd(&hist[d >> 8], 1);
    }
    __syncthreads();
    if (t < NBUCK) {
        int h = hist[t];
        cnt[t * PART_BLOCKS + blockIdx.x] = h;   // always write (k_pb scans all)
        if (h > 0) atomicAdd(&gbsum[t], h);
    }
}

// ---- exclusive scan of bucket sums -> bbase; total -> rowptr[N] ----
__global__ void k_s2(const int* __restrict__ gbsum, int* __restrict__ bbase,
                     int* __restrict__ rowptr) {
    __shared__ int sc[256];
    int t = threadIdx.x;
    int v = (t < NBUCK) ? gbsum[t] : 0;
    sc[t] = v;
    __syncthreads();
    for (int off = 1; off < 256; off <<= 1) {
        int u = (t >= off) ? sc[t - off] : 0;
        __syncthreads();
        sc[t] += u;
        __syncthreads();
    }
    if (t < NBUCK) bbase[t] = sc[t] - v;
    if (t == 255) rowptr[N_NODES] = sc[255];
}

// ---- per-bin scan over blocks: cnt[bin][blk] -> absolute write base ----
__global__ void k_pb(const int* __restrict__ bbase, int* __restrict__ cnt) {
    __shared__ int sc[256];
    int b = blockIdx.x, t = threadIdx.x;
    int v = cnt[b * PART_BLOCKS + t];
    sc[t] = v;
    __syncthreads();
    for (int off = 1; off < 256; off <<= 1) {
        int u = (t >= off) ? sc[t - off] : 0;
        __syncthreads();
        sc[t] += u;
        __syncthreads();
    }
    cnt[b * PART_BLOCKS + t] = bbase[b] + sc[t] - v;
}

// ---- pass 2: single-pass scatter into bucket-sorted ebuf, packed (src<<8|d&255) ----
__global__ void k_part(const int* __restrict__ ei, const int* __restrict__ flags,
                       const int* __restrict__ cnt, unsigned int* __restrict__ ebuf) {
    __shared__ int cur[NBUCK];
    int t = threadIdx.x, blk = blockIdx.x;
    int i64f = flags[1];
    const int CH = (N_EDGES + PART_BLOCKS - 1) / PART_BLOCKS;
    int lo = blk * CH;
    int hi = lo + CH; if (hi > N_EDGES) hi = N_EDGES;
    if (t < NBUCK) cur[t] = cnt[t * PART_BLOCKS + blk];
    __syncthreads();
    for (int i = lo + t; i < hi; i += 256) {
        int s = ld_edge(ei, i64f, (size_t)i);
        int d = ld_edge(ei, i64f, (size_t)N_EDGES + i);
        if ((unsigned)d < (unsigned)N_NODES && (unsigned)s < (unsigned)N_NODES) {
            int pos = atomicAdd(&cur[d >> 8], 1);
            if ((unsigned)pos < (unsigned)N_EDGES)
                ebuf[pos] = ((unsigned)s << 8) | (unsigned)(d & 255);
        }
    }
}

// ---- per-bucket: LDS degree histogram -> rowptr + dinv + CSR fill ----
__global__ void k_cfill(const unsigned int* __restrict__ ebuf,
                        const int* __restrict__ bbase, const int* __restrict__ gbsum,
                        int* __restrict__ rowptr, float* __restrict__ dinv,
                        int* __restrict__ col) {
    __shared__ int dcnt[256];
    __shared__ int sc[256];
    __shared__ int cur[256];
    int b = blockIdx.x, t = threadIdx.x;
    int e0 = bbase[b];
    int e1 = e0 + gbsum[b];
    dcnt[t] = 0;
    __syncthreads();
    for (int e = e0 + t; e < e1; e += 256)
        atomicAdd(&dcnt[ebuf[e] & 255u], 1);
    __syncthreads();
    int v = dcnt[t];
    sc[t] = v;
    __syncthreads();
    for (int off = 1; off < 256; off <<= 1) {
        int u = (t >= off) ? sc[t - off] : 0;
        __syncthreads();
        sc[t] += u;
        __syncthreads();
    }
    int row0 = e0 + sc[t] - v;
    cur[t] = row0;
    int idx = b * 256 + t;
    if (idx < N_NODES) {
        rowptr[idx] = row0;
        dinv[idx] = rsqrtf((float)(v + 1));  // +1 self-loop
    }
    __syncthreads();
    for (int e = e0 + t; e < e1; e += 256) {
        unsigned int x = ebuf[e];
        int p = atomicAdd(&cur[x & 255u], 1);
        if ((unsigned)p < (unsigned)N_EDGES) col[p] = (int)(x >> 8);
    }
}

// ---- W1T[n][k] = bf16(W1[k][n]) ----
__global__ void k_tw1(const void* __restrict__ W1, const int* __restrict__ flags,
                      u16* __restrict__ W1T) {
    int i = blockIdx.x * blockDim.x + threadIdx.x;
    if (i < DIM_IN * DIM_HID) {
        int n = i >> 9;
        int k = i & 511;
        if (flags[0]) W1T[i] = f2bf(((const float*)W1)[k * DIM_HID + n]);
        else          W1T[i] = ((const u16*)W1)[k * DIM_HID + n];
    }
}

// ---- GEMM1 (MFMA 16x16x32 bf16): hs = bf16((x @ W1) * dinv[row]) ----
__launch_bounds__(256)
__global__ void k_gemm1(const void* __restrict__ xraw, const u16* __restrict__ W1T,
                        const int* __restrict__ flags, const float* __restrict__ dinv,
                        u16* __restrict__ hs) {
    int f32f = flags[0];
    int wave = threadIdx.x >> 6;
    int lane = threadIdx.x & 63;
    int m16 = lane & 15;
    int quad = lane >> 4;
    int rbase = blockIdx.x * 64 + wave * 16;
    int ra = rbase + m16;
    if (ra > N_NODES - 1) ra = N_NODES - 1;
    const u16*   xrow_b = (const u16*)xraw   + (size_t)ra * DIM_IN + quad * 8;
    const float* xrow_f = (const float*)xraw + (size_t)ra * DIM_IN + quad * 8;
    const u16* wrow = W1T + (size_t)m16 * DIM_IN + quad * 8;

    f32x4 acc0 = {0.f, 0.f, 0.f, 0.f};
    f32x4 acc1 = {0.f, 0.f, 0.f, 0.f};
    f32x4 acc2 = {0.f, 0.f, 0.f, 0.f};
    f32x4 acc3 = {0.f, 0.f, 0.f, 0.f};

    for (int ks = 0; ks < DIM_IN / 32; ++ks) {
        bf16x8 a;
        if (f32f) {
            const float4* q = reinterpret_cast<const float4*>(xrow_f + ks * 32);
            float4 p0 = q[0], p1 = q[1];
            union { bf16x8 v; u16 s[8]; } u;
            u.s[0] = f2bf(p0.x); u.s[1] = f2bf(p0.y); u.s[2] = f2bf(p0.z); u.s[3] = f2bf(p0.w);
            u.s[4] = f2bf(p1.x); u.s[5] = f2bf(p1.y); u.s[6] = f2bf(p1.z); u.s[7] = f2bf(p1.w);
            a = u.v;
        } else {
            a = *reinterpret_cast<const bf16x8*>(xrow_b + ks * 32);
        }
        bf16x8 b0 = *reinterpret_cast<const bf16x8*>(wrow + ks * 32);
        bf16x8 b1 = *reinterpret_cast<const bf16x8*>(wrow + ks * 32 + 16 * DIM_IN);
        bf16x8 b2 = *reinterpret_cast<const bf16x8*>(wrow + ks * 32 + 32 * DIM_IN);
        bf16x8 b3 = *reinterpret_cast<const bf16x8*>(wrow + ks * 32 + 48 * DIM_IN);
        acc0 = __builtin_amdgcn_mfma_f32_16x16x32_bf16(a, b0, acc0, 0, 0, 0);
        acc1 = __builtin_amdgcn_mfma_f32_16x16x32_bf16(a, b1, acc1, 0, 0, 0);
        acc2 = __builtin_amdgcn_mfma_f32_16x16x32_bf16(a, b2, acc2, 0, 0, 0);
        acc3 = __builtin_amdgcn_mfma_f32_16x16x32_bf16(a, b3, acc3, 0, 0, 0);
    }

#pragma unroll
    for (int i = 0; i < 4; ++i) {
        int r = rbase + quad * 4 + i;
        if (r < N_NODES) {
            float dv = dinv[r];
            u16* orow = hs + (size_t)r * DIM_HID;
            orow[ 0 + m16] = f2bf(acc0[i] * dv);
            orow[16 + m16] = f2bf(acc1[i] * dv);
            orow[32 + m16] = f2bf(acc2[i] * dv);
            orow[48 + m16] = f2bf(acc3[i] * dv);
        }
    }
}

// ---- layer-1 pull aggregation + fused GEMM2, software-pipelined gather ----
__launch_bounds__(256)
__global__ void k_agg1(const u16* __restrict__ hs, const int* __restrict__ rowptr,
                       const int* __restrict__ col, const float* __restrict__ dinv,
                       const void* __restrict__ b1, const void* __restrict__ W2,
                       const int* __restrict__ flags, float* __restrict__ zs) {
    int f32f = flags[0];
    int wave = threadIdx.x >> 6;
    int lane = threadIdx.x & 63;
    int d = blockIdx.x * 4 + wave;
    if (d >= N_NODES) return;
    int start = rowptr[d], end = rowptr[d + 1];
    if (start < 0) start = 0;
    if (end > N_EDGES) end = N_EDGES;
    if (end < start) end = start;

    float acc = 0.f;
    int n8 = (end - start) >> 3;
    int cA[8];
    if (n8 > 0) {
        const int* cp = col + start;
#pragma unroll
        for (int j = 0; j < 8; ++j) cA[j] = cp[j];
        for (int it = 0; it < n8; ++it) {
            // prefetch next 8 indices while gathering with the current 8
            int cB[8];
            if (it + 1 < n8) {
                const int* cpn = col + start + (it + 1) * 8;
#pragma unroll
                for (int j = 0; j < 8; ++j) cB[j] = cpn[j];
            } else {
#pragma unroll
                for (int j = 0; j < 8; ++j) cB[j] = 0;
            }
            float v[8];
#pragma unroll
            for (int j = 0; j < 8; ++j) v[j] = bf2f(hs[(size_t)cA[j] * DIM_HID + lane]);
#pragma unroll
            for (int j = 0; j < 8; ++j) acc += v[j];
#pragma unroll
            for (int j = 0; j < 8; ++j) cA[j] = cB[j];
        }
    }
    for (int e = start + n8 * 8; e < end; ++e)
        acc += bf2f(hs[(size_t)col[e] * DIM_HID + lane]);
    acc += bf2f(hs[(size_t)d * DIM_HID + lane]);  // self loop

    float b1v = f32f ? ((const float*)b1)[lane] : bf2f(((const u16*)b1)[lane]);
    float dv = dinv[d];
    float h2 = fmaxf(acc * dv + b1v, 0.f);

    float p[7];
#pragma unroll
    for (int f = 0; f < 7; ++f) {
        float w = f32f ? ((const float*)W2)[lane * DIM_OUT + f]
                       : bf2f(((const u16*)W2)[lane * DIM_OUT + f]);
        p[f] = h2 * w;
    }
#pragma unroll
    for (int off = 32; off >= 1; off >>= 1) {
#pragma unroll
        for (int f = 0; f < 7; ++f) p[f] += __shfl_xor(p[f], off);
    }
    if (lane == 0) {
#pragma unroll
        for (int f = 0; f < 7; ++f) zs[(size_t)d * 8 + f] = p[f] * dv;
        zs[(size_t)d * 8 + 7] = 0.f;
    }
}

// ---- layer-2 pull aggregation: out (f32) ----
__launch_bounds__(256)
__global__ void k_agg2(const float* __restrict__ zs, const int* __restrict__ rowptr,
                       const int* __restrict__ col, const float* __restrict__ dinv,
                       const void* __restrict__ b2, const int* __restrict__ flags,
                       float* __restrict__ out) {
    int f32f = flags[0];
    int wave = threadIdx.x >> 6;
    int lane = threadIdx.x & 63;
    int d = blockIdx.x * 4 + wave;
    if (d >= N_NODES) return;
    int f = lane & 7;
    int g = lane >> 3;
    int start = rowptr[d], end = rowptr[d + 1];
    if (start < 0) start = 0;
    if (end > N_EDGES) end = N_EDGES;
    if (end < start) end = start;

    float acc = 0.f;
    for (int e = start + g; e < end; e += 8)
        acc += zs[(size_t)col[e] * 8 + f];

    acc += __shfl_xor(acc, 8);
    acc += __shfl_xor(acc, 16);
    acc += __shfl_xor(acc, 32);

    if (lane < 7) {
        float b2v = f32f ? ((const float*)b2)[lane] : bf2f(((const u16*)b2)[lane]);
        float tot = (acc + zs[(size_t)d * 8 + lane]) * dinv[d] + b2v;
        out[(size_t)d * DIM_OUT + lane] = tot;
    }
}

extern "C" void kernel_launch(void* const* d_in, const int* in_sizes, int n_in,
                              void* d_out, int out_size, void* d_ws, size_t ws_size,
                              hipStream_t stream) {
    const void* x  = d_in[0];
    const int*  ei = (const int*)d_in[1];
    const void* W1 = d_in[2];
    const void* b1 = d_in[3];
    const void* W2 = d_in[4];
    const void* b2 = d_in[5];

    char* ws = (char*)d_ws;
    size_t off = 0;
    auto alloc = [&](size_t bytes) -> void* {
        void* p = ws + off;
        off = (off + bytes + 255) & ~(size_t)255;
        return p;
    };
    int*   flags  = (int*)alloc(32);
    int*   rowptr = (int*)alloc((size_t)(N_NODES + 1) * 4);
    int*   gbsum  = (int*)alloc((size_t)NBUCK * 4);
    int*   bbase  = (int*)alloc((size_t)NBUCK * 4);
    int*   cnt    = (int*)alloc((size_t)NBUCK * PART_BLOCKS * 4);
    float* dinv   = (float*)alloc((size_t)N_NODES * 4);
    u16*   W1T    = (u16*)alloc((size_t)DIM_IN * DIM_HID * 2);
    unsigned int* ebuf = (unsigned int*)alloc((size_t)N_EDGES * 4);
    int*   colb   = (int*)alloc((size_t)N_EDGES * 4);
    u16*   hs     = (u16*)alloc((size_t)N_NODES * DIM_HID * 2);
    float* zs     = (float*)alloc((size_t)N_NODES * 8 * 4);
    float* out    = (float*)d_out;

    hipMemsetAsync(gbsum, 0, (size_t)NBUCK * 4, stream);
    k_detect<<<1, 64, 0, stream>>>((const u16*)x, ei, flags);
    k_count<<<PART_BLOCKS, 256, 0, stream>>>(ei, flags, gbsum, cnt);
    k_s2   <<<1, 256, 0, stream>>>(gbsum, bbase, rowptr);
    k_pb   <<<NBUCK, 256, 0, stream>>>(bbase, cnt);
    k_part <<<PART_BLOCKS, 256, 0, stream>>>(ei, flags, cnt, ebuf);
    k_cfill<<<NBUCK, 256, 0, stream>>>(ebuf, bbase, gbsum, rowptr, dinv, colb);
    k_tw1  <<<(DIM_IN * DIM_HID + 255) / 256, 256, 0, stream>>>(W1, flags, W1T);
    k_gemm1<<<(N_NODES + 63) / 64, 256, 0, stream>>>(x, W1T, flags, dinv, hs);
    k_agg1 <<<(N_NODES + 3) / 4, 256, 0, stream>>>(hs, rowptr, colb, dinv, b1, W2, flags, zs);
    k_agg2 <<<(N_NODES + 3) / 4, 256, 0, stream>>>(zs, rowptr, colb, dinv, b2, flags, out);
}